// Round 5
// baseline (8467.044 us; speedup 1.0000x reference)
//
#include <hip/hip_runtime.h>
#include <hip/hip_bf16.h>

// ---------------------------------------------------------------------------
// LiteCNNMoEClassifier on MI355X — round 5.
// Theory (from R4's NaN): inputs AND output are fp32, exactly as documented.
//   R1 crashed on ws overrun (272MB); R2 failed only because it wrote bf16
//   into the fp32 out buffer; R3/R4 failed reading fp32 as bf16.
// This round: R1 dtypes + R4 memory discipline (CHUNK=256, ws ~37.8MB) +
// defensive index clamps. Stem pure fp32 -> router top-2 exact.
// ---------------------------------------------------------------------------

// ---------------- Kernel 1: conv1+bn1+relu fused into conv2+bn2+relu -------
// grid (256, 2): image x 64-output-channel half. block 256 = 16x16 spatial.
__global__ __launch_bounds__(256) void conv12_kernel(
    const float* __restrict__ x,
    const float* __restrict__ w1, const float* __restrict__ cb1,
    const float* __restrict__ g1, const float* __restrict__ beta1,
    const float* __restrict__ w2, const float* __restrict__ cb2,
    const float* __restrict__ g2, const float* __restrict__ beta2,
    float* __restrict__ h2out)
{
    __shared__ float xt[3 * 34 * 34];    // padded input image (13.6 KB)
    __shared__ float h1t[8 * 34 * 34];   // padded h1 chunk, 8 ch (37 KB)
    const int img = blockIdx.x;
    const int ocb = blockIdx.y * 64;
    const int tid = threadIdx.x;
    const float inv = 1.0f / sqrtf(1.0f + 1e-5f);   // BN: var=1, eps=1e-5

    for (int i = tid; i < 3 * 34 * 34; i += 256) xt[i] = 0.f;
    for (int i = tid; i < 8 * 34 * 34; i += 256) h1t[i] = 0.f;
    __syncthreads();

    // load fp32 image into padded LDS
    const float4* xi = (const float4*)(x + (size_t)img * 3072);
    for (int i = tid; i < 768; i += 256) {
        float4 v = xi[i];
        int flat = i * 4;
        int ic = flat >> 10, p = flat & 1023, y = p >> 5, xx = p & 31;
        float* dst = &xt[ic * 1156 + (y + 1) * 34 + xx + 1];
        dst[0] = v.x; dst[1] = v.y; dst[2] = v.z; dst[3] = v.w;
    }
    __syncthreads();

    const int oy = tid >> 4, ox = tid & 15;      // conv2 output position
    const int yy = tid >> 3, x0 = (tid & 7) * 4; // conv1 output row / 4-col group

    float acc[64];
    #pragma unroll
    for (int i = 0; i < 64; ++i) acc[i] = 0.f;

    for (int ci = 0; ci < 8; ++ci) {
        for (int j = 0; j < 8; ++j) {               // j uniform -> scalar weight loads
            const int oc1 = ci * 8 + j;
            float s0 = 0.f, s1 = 0.f, s2 = 0.f, s3 = 0.f;
            #pragma unroll
            for (int ic = 0; ic < 3; ++ic) {
                #pragma unroll
                for (int dy = 0; dy < 3; ++dy) {
                    const float* row = &xt[ic * 1156 + (yy + dy) * 34 + x0];
                    float r0 = row[0], r1 = row[1], r2 = row[2];
                    float r3 = row[3], r4 = row[4], r5 = row[5];
                    const float* wp = w1 + oc1 * 27 + ic * 9 + dy * 3;
                    float wa = wp[0], wb = wp[1], wc = wp[2];
                    s0 += r0 * wa + r1 * wb + r2 * wc;
                    s1 += r1 * wa + r2 * wb + r3 * wc;
                    s2 += r2 * wa + r3 * wb + r4 * wc;
                    s3 += r3 * wa + r4 * wb + r5 * wc;
                }
            }
            float A  = g1[oc1] * inv;
            float Bb = cb1[oc1] * A + beta1[oc1];
            float* dst = &h1t[j * 1156 + (yy + 1) * 34 + x0 + 1];
            dst[0] = fmaxf(s0 * A + Bb, 0.f);
            dst[1] = fmaxf(s1 * A + Bb, 0.f);
            dst[2] = fmaxf(s2 * A + Bb, 0.f);
            dst[3] = fmaxf(s3 * A + Bb, 0.f);
        }
        __syncthreads();

        for (int ic8 = 0; ic8 < 8; ++ic8) {
            float v[9];
            #pragma unroll
            for (int dy = 0; dy < 3; ++dy)
                #pragma unroll
                for (int dx = 0; dx < 3; ++dx)
                    v[dy * 3 + dx] = h1t[ic8 * 1156 + (2 * oy + dy) * 34 + 2 * ox + dx];
            const int icg = ci * 8 + ic8;
            #pragma unroll
            for (int oc = 0; oc < 64; ++oc) {       // uniform weight index -> s_load
                const float* wp = w2 + ((size_t)(ocb + oc) * 64 + icg) * 9;
                float s = acc[oc];
                #pragma unroll
                for (int k = 0; k < 9; ++k) s += v[k] * wp[k];
                acc[oc] = s;
            }
        }
        __syncthreads();
    }

    float* outp = h2out + ((size_t)img * 128 + ocb) * 256 + oy * 16 + ox;
    #pragma unroll
    for (int oc = 0; oc < 64; ++oc) {
        int c = ocb + oc;
        float A  = g2[c] * inv;
        float Bb = cb2[c] * A + beta2[c];
        outp[(size_t)oc * 256] = fmaxf(acc[oc] * A + Bb, 0.f);
    }
}

// ---------------- Kernel 2: conv3+bn3+relu + global avg pool ---------------
// grid 256 (image in chunk). block 512 = 64 spatial x 8 oc-groups (32 oc each).
__global__ __launch_bounds__(512) void conv3pool_kernel(
    const float* __restrict__ h2, const float* __restrict__ w3,
    const float* __restrict__ cb3, const float* __restrict__ g3,
    const float* __restrict__ beta3, float* __restrict__ feats)
{
    __shared__ float smem[32 * 16 * 18];   // 36 KB: 32-ch chunk, col-padded
    const int img = blockIdx.x;
    const int tid = threadIdx.x;
    const int sp = tid & 63, oy = sp >> 3, ox = sp & 7;
    const int ocg = __builtin_amdgcn_readfirstlane(tid >> 6);  // wave-uniform
    const float inv = 1.0f / sqrtf(1.0f + 1e-5f);

    float acc[32];
    #pragma unroll
    for (int i = 0; i < 32; ++i) acc[i] = 0.f;

    for (int i = tid; i < 32 * 16; i += 512) smem[i * 18] = 0.f;  // left pad col

    const float* h2i = h2 + (size_t)img * (128 * 256);
    for (int cc = 0; cc < 4; ++cc) {
        const float4* src = (const float4*)(h2i + (size_t)cc * 32 * 256);
        for (int i = tid; i < 2048; i += 512) {
            float4 v = src[i];
            int flat = i * 4, ic = flat >> 8, p = flat & 255, y = p >> 4, xx = p & 15;
            float* dst = &smem[ic * 288 + y * 18 + xx + 1];
            dst[0] = v.x; dst[1] = v.y; dst[2] = v.z; dst[3] = v.w;
        }
        __syncthreads();

        for (int ic = 0; ic < 32; ++ic) {
            float v[9];
            #pragma unroll
            for (int dy = 0; dy < 3; ++dy) {
                int r = 2 * oy - 1 + dy;           // only r=-1 invalid
                #pragma unroll
                for (int dx = 0; dx < 3; ++dx)
                    v[dy * 3 + dx] = (r >= 0) ? smem[ic * 288 + r * 18 + 2 * ox + dx] : 0.f;
            }
            const int icg = cc * 32 + ic;
            #pragma unroll
            for (int i = 0; i < 32; ++i) {          // ocg wave-uniform -> s_load weights
                const float* wp = w3 + ((size_t)(ocg * 32 + i) * 128 + icg) * 9;
                float s = acc[i];
                #pragma unroll
                for (int k = 0; k < 9; ++k) s += v[k] * wp[k];
                acc[i] = s;
            }
        }
        __syncthreads();
    }

    float keep = 0.f;
    #pragma unroll
    for (int i = 0; i < 32; ++i) {
        int c = ocg * 32 + i;
        float A  = g3[c] * inv;
        float Bb = cb3[c] * A + beta3[c];
        float val = fmaxf(acc[i] * A + Bb, 0.f);
        #pragma unroll
        for (int off = 32; off; off >>= 1) val += __shfl_xor(val, off);
        if (sp == i) keep = val;
    }
    if (sp < 32)
        feats[(size_t)img * 256 + ocg * 32 + sp] = keep * (1.f / 64.f);
}

// ---------------- Kernel 3: router + top-2 + softmax gates -----------------
// grid 512, block 256 = 4 waves, one token per wave.
__global__ __launch_bounds__(256) void router_kernel(
    const float* __restrict__ feats, const float* __restrict__ rw,
    const float* __restrict__ rb, int* __restrict__ tidx,
    float* __restrict__ tgate)
{
    const int t = blockIdx.x * 4 + (threadIdx.x >> 6);
    const int lane = threadIdx.x & 63;
    float4 f = ((const float4*)(feats + (size_t)t * 256))[lane];
    float lg[16];
    #pragma unroll
    for (int e = 0; e < 16; ++e) {
        float4 w = ((const float4*)(rw + (size_t)e * 256))[lane];
        float p = f.x * w.x + f.y * w.y + f.z * w.z + f.w * w.w;
        #pragma unroll
        for (int off = 32; off; off >>= 1) p += __shfl_xor(p, off);
        lg[e] = p + rb[e];
    }
    // top-2, lowest index wins ties (matches lax.top_k)
    int i1 = 0; float m1 = lg[0];
    #pragma unroll
    for (int e = 1; e < 16; ++e) if (lg[e] > m1) { m1 = lg[e]; i1 = e; }
    int i2 = -1; float m2 = -1e30f;
    #pragma unroll
    for (int e = 0; e < 16; ++e)
        if (e != i1 && lg[e] > m2) { m2 = lg[e]; i2 = e; }
    if (i2 < 0) i2 = 0;                 // defensive: never emit -1
    float ex = expf(m2 - m1);
    float gA = 1.f / (1.f + ex);
    float gB = ex / (1.f + ex);
    if (lane == 0) {
        tidx[t * 2] = i1; tidx[t * 2 + 1] = i2;
        tgate[t * 2] = gA; tgate[t * 2 + 1] = gB;
    }
}

// ---------------- Kernel 4: top-2 expert MLP dispatch ----------------------
// grid 2048 (token), block 256.
__global__ __launch_bounds__(256) void moe_kernel(
    const float* __restrict__ feats, const int* __restrict__ tidx,
    const float* __restrict__ tgate,
    const float* __restrict__ ew1, const float* __restrict__ eb1,
    const float* __restrict__ ew2, const float* __restrict__ eb2,
    float* __restrict__ mixed)
{
    __shared__ float fr[256];
    __shared__ float hl[1024];
    const int t = blockIdx.x, tid = threadIdx.x;
    fr[tid] = feats[(size_t)t * 256 + tid];
    float macc = 0.f;
    for (int s = 0; s < 2; ++s) {
        const int e = tidx[t * 2 + s] & 15;   // clamp: OOB-proof
        const float g = tgate[t * 2 + s];
        __syncthreads();   // fr visible (s=0); hl safe to overwrite (s=1)
        // layer1: thread computes hidden units 4*tid..4*tid+3
        const float* W1 = ew1 + (size_t)e * (256 * 1024);
        float4 a = ((const float4*)(eb1 + (size_t)e * 1024))[tid];
        for (int d = 0; d < 256; ++d) {
            const float fv = fr[d];
            float4 w = ((const float4*)(W1 + (size_t)d * 1024))[tid];
            a.x += fv * w.x; a.y += fv * w.y; a.z += fv * w.z; a.w += fv * w.w;
        }
        a.x = fmaxf(a.x, 0.f); a.y = fmaxf(a.y, 0.f);
        a.z = fmaxf(a.z, 0.f); a.w = fmaxf(a.w, 0.f);
        ((float4*)hl)[tid] = a;
        __syncthreads();
        // layer2: thread computes output dim i = tid
        const float* W2 = ew2 + (size_t)e * (1024 * 256);
        float o0 = eb2[(size_t)e * 256 + tid], o1 = 0.f, o2 = 0.f, o3 = 0.f;
        for (int h = 0; h < 1024; h += 4) {
            o0 += hl[h]     * W2[(size_t)h       * 256 + tid];
            o1 += hl[h + 1] * W2[(size_t)(h + 1) * 256 + tid];
            o2 += hl[h + 2] * W2[(size_t)(h + 2) * 256 + tid];
            o3 += hl[h + 3] * W2[(size_t)(h + 3) * 256 + tid];
        }
        macc += g * ((o0 + o1) + (o2 + o3));
    }
    mixed[(size_t)t * 256 + tid] = macc;
}

// ---------------- Kernel 5: classifier head (fp32 out) ---------------------
// grid 512, block 256: 4 tokens per block, thread covers 4 columns.
__global__ __launch_bounds__(256) void head_kernel(
    const float* __restrict__ mixed, const float* __restrict__ hw,
    const float* __restrict__ hb, float* __restrict__ out)
{
    const int t0 = blockIdx.x * 4, tid = threadIdx.x;
    const float* m0 = mixed + (size_t)t0 * 256;   // uniform index -> scalar loads
    #pragma unroll
    for (int r = 0; r < 4; ++r) {
        int c = tid + 256 * r;
        if (c < 1000) {
            const float4* wr = (const float4*)(hw + (size_t)c * 256);
            float a0 = 0.f, a1 = 0.f, a2 = 0.f, a3 = 0.f;
            for (int d = 0; d < 64; ++d) {
                float4 w = wr[d];
                const float* q0 = m0 + 4 * d;
                a0 += w.x * q0[0]   + w.y * q0[1]   + w.z * q0[2]   + w.w * q0[3];
                a1 += w.x * q0[256] + w.y * q0[257] + w.z * q0[258] + w.w * q0[259];
                a2 += w.x * q0[512] + w.y * q0[513] + w.z * q0[514] + w.w * q0[515];
                a3 += w.x * q0[768] + w.y * q0[769] + w.z * q0[770] + w.w * q0[771];
            }
            float bb = hb[c];
            out[(size_t)(t0 + 0) * 1000 + c] = a0 + bb;
            out[(size_t)(t0 + 1) * 1000 + c] = a1 + bb;
            out[(size_t)(t0 + 2) * 1000 + c] = a2 + bb;
            out[(size_t)(t0 + 3) * 1000 + c] = a3 + bb;
        }
    }
}

// ---------------------------------------------------------------------------
extern "C" void kernel_launch(void* const* d_in, const int* in_sizes, int n_in,
                              void* d_out, int out_size, void* d_ws, size_t ws_size,
                              hipStream_t stream)
{
    const float* x       = (const float*)d_in[0];
    const float* conv1_w = (const float*)d_in[1];
    const float* conv1_b = (const float*)d_in[2];
    const float* bn1_g   = (const float*)d_in[3];
    const float* bn1_b   = (const float*)d_in[4];
    const float* conv2_w = (const float*)d_in[5];
    const float* conv2_b = (const float*)d_in[6];
    const float* bn2_g   = (const float*)d_in[7];
    const float* bn2_b   = (const float*)d_in[8];
    const float* conv3_w = (const float*)d_in[9];
    const float* conv3_b = (const float*)d_in[10];
    const float* bn3_g   = (const float*)d_in[11];
    const float* bn3_b   = (const float*)d_in[12];
    const float* router_w = (const float*)d_in[13];
    const float* router_b = (const float*)d_in[14];
    const float* ew1 = (const float*)d_in[15];
    const float* eb1 = (const float*)d_in[16];
    const float* ew2 = (const float*)d_in[17];
    const float* eb2 = (const float*)d_in[18];
    const float* head_w = (const float*)d_in[19];
    const float* head_b = (const float*)d_in[20];
    // top_k (d_in[21]) fixed at 2.

    // ---- workspace layout (total ~37.8 MB) --------------------------------
    char* ws = (char*)d_ws;
    size_t off = 0;
    auto A = [&](size_t bytes) -> char* {
        char* p = ws + off; off += (bytes + 255) & ~(size_t)255; return p;
    };
    float* h2    = (float*)A(256ull * 128 * 256 * 4);   // 33.55 MB (per chunk)
    float* feats = (float*)A(2048ull * 256 * 4);        //  2.10 MB
    float* mixed = (float*)A(2048ull * 256 * 4);        //  2.10 MB
    int*   tidx  = (int*)  A(2048ull * 2 * 4);
    float* tgate = (float*)A(2048ull * 2 * 4);
    float* outp  = (float*)d_out;

    // ---- stem (8 chunks of 256 images, h2 reused) -------------------------
    const int CHUNK = 256;
    for (int c0 = 0; c0 < 2048; c0 += CHUNK) {
        conv12_kernel<<<dim3(CHUNK, 2), 256, 0, stream>>>(
            x + (size_t)c0 * 3072, conv1_w, conv1_b, bn1_g, bn1_b,
            conv2_w, conv2_b, bn2_g, bn2_b, h2);
        conv3pool_kernel<<<CHUNK, 512, 0, stream>>>(
            h2, conv3_w, conv3_b, bn3_g, bn3_b, feats + (size_t)c0 * 256);
    }
    router_kernel<<<512, 256, 0, stream>>>(feats, router_w, router_b, tidx, tgate);
    moe_kernel<<<2048, 256, 0, stream>>>(feats, tidx, tgate, ew1, eb1, ew2, eb2, mixed);
    head_kernel<<<512, 256, 0, stream>>>(mixed, head_w, head_b, outp);
}

// Round 8
// 6181.723 us; speedup vs baseline: 1.3697x; 1.3697x over previous
//
#include <hip/hip_runtime.h>
#include <hip/hip_bf16.h>

// ---------------------------------------------------------------------------
// LiteCNNMoEClassifier on MI355X — round 8 (= round 6/7 resubmitted; GPU
// acquisition timed out twice before it ever ran).
// R5 counters: conv12 VALUBusy 20%, Occupancy 24% (2 blocks/CU), latency-
// bound; bank conflicts negligible (0.6%). Fix: smaller LDS + more blocks.
//   conv12:    oc x4 split, 4-ch h1 chunks, LDS 32.4KB, grid (512,4).
//   conv3pool: oc x2 split, 16-ch smem chunks, LDS 18.4KB, grid (512,2).
//   CHUNK=512 (ws 71.36MB = R2-proven safe footprint).
// Math identical to the passing R5 kernel (stem pure fp32 -> routing exact).
// ---------------------------------------------------------------------------

// ---------------- Kernel 1: conv1+bn1+relu fused into conv2+bn2+relu -------
// grid (512, 4): image x 32-output-channel quarter. block 256 = 16x16 spatial.
__global__ __launch_bounds__(256) void conv12_kernel(
    const float* __restrict__ x,
    const float* __restrict__ w1, const float* __restrict__ cb1,
    const float* __restrict__ g1, const float* __restrict__ beta1,
    const float* __restrict__ w2, const float* __restrict__ cb2,
    const float* __restrict__ g2, const float* __restrict__ beta2,
    float* __restrict__ h2out)
{
    __shared__ float xt[3 * 34 * 34];    // padded input image (13.9 KB)
    __shared__ float h1t[4 * 34 * 34];   // padded h1 chunk, 4 ch (18.5 KB)
    const int img = blockIdx.x;
    const int ocb = blockIdx.y * 32;
    const int tid = threadIdx.x;
    const float inv = 1.0f / sqrtf(1.0f + 1e-5f);   // BN: var=1, eps=1e-5

    for (int i = tid; i < 3 * 34 * 34; i += 256) xt[i] = 0.f;
    for (int i = tid; i < 4 * 34 * 34; i += 256) h1t[i] = 0.f;
    __syncthreads();

    // load fp32 image into padded LDS
    const float4* xi = (const float4*)(x + (size_t)img * 3072);
    for (int i = tid; i < 768; i += 256) {
        float4 v = xi[i];
        int flat = i * 4;
        int ic = flat >> 10, p = flat & 1023, y = p >> 5, xx = p & 31;
        float* dst = &xt[ic * 1156 + (y + 1) * 34 + xx + 1];
        dst[0] = v.x; dst[1] = v.y; dst[2] = v.z; dst[3] = v.w;
    }
    __syncthreads();

    const int oy = tid >> 4, ox = tid & 15;      // conv2 output position
    const int yy = tid >> 3, x0 = (tid & 7) * 4; // conv1 output row / 4-col group

    float acc[32];
    #pragma unroll
    for (int i = 0; i < 32; ++i) acc[i] = 0.f;

    for (int ci = 0; ci < 16; ++ci) {            // 4 h1 channels per iteration
        for (int j = 0; j < 4; ++j) {            // j uniform -> scalar weight loads
            const int oc1 = ci * 4 + j;
            float s0 = 0.f, s1 = 0.f, s2 = 0.f, s3 = 0.f;
            #pragma unroll
            for (int ic = 0; ic < 3; ++ic) {
                #pragma unroll
                for (int dy = 0; dy < 3; ++dy) {
                    const float* row = &xt[ic * 1156 + (yy + dy) * 34 + x0];
                    float r0 = row[0], r1 = row[1], r2 = row[2];
                    float r3 = row[3], r4 = row[4], r5 = row[5];
                    const float* wp = w1 + oc1 * 27 + ic * 9 + dy * 3;
                    float wa = wp[0], wb = wp[1], wc = wp[2];
                    s0 += r0 * wa + r1 * wb + r2 * wc;
                    s1 += r1 * wa + r2 * wb + r3 * wc;
                    s2 += r2 * wa + r3 * wb + r4 * wc;
                    s3 += r3 * wa + r4 * wb + r5 * wc;
                }
            }
            float A  = g1[oc1] * inv;
            float Bb = cb1[oc1] * A + beta1[oc1];
            float* dst = &h1t[j * 1156 + (yy + 1) * 34 + x0 + 1];
            dst[0] = fmaxf(s0 * A + Bb, 0.f);
            dst[1] = fmaxf(s1 * A + Bb, 0.f);
            dst[2] = fmaxf(s2 * A + Bb, 0.f);
            dst[3] = fmaxf(s3 * A + Bb, 0.f);
        }
        __syncthreads();

        for (int ic4 = 0; ic4 < 4; ++ic4) {
            float v[9];
            #pragma unroll
            for (int dy = 0; dy < 3; ++dy)
                #pragma unroll
                for (int dx = 0; dx < 3; ++dx)
                    v[dy * 3 + dx] = h1t[ic4 * 1156 + (2 * oy + dy) * 34 + 2 * ox + dx];
            const int icg = ci * 4 + ic4;
            #pragma unroll
            for (int oc = 0; oc < 32; ++oc) {    // uniform weight index -> s_load
                const float* wp = w2 + ((size_t)(ocb + oc) * 64 + icg) * 9;
                float s = acc[oc];
                #pragma unroll
                for (int k = 0; k < 9; ++k) s += v[k] * wp[k];
                acc[oc] = s;
            }
        }
        __syncthreads();
    }

    float* outp = h2out + ((size_t)img * 128 + ocb) * 256 + oy * 16 + ox;
    #pragma unroll
    for (int oc = 0; oc < 32; ++oc) {
        int c = ocb + oc;
        float A  = g2[c] * inv;
        float Bb = cb2[c] * A + beta2[c];
        outp[(size_t)oc * 256] = fmaxf(acc[oc] * A + Bb, 0.f);
    }
}

// ---------------- Kernel 2: conv3+bn3+relu + global avg pool ---------------
// grid (512, 2): image x 128-oc half. block 256 = 64 spatial x 4 waves(32 oc).
__global__ __launch_bounds__(256) void conv3pool_kernel(
    const float* __restrict__ h2, const float* __restrict__ w3,
    const float* __restrict__ cb3, const float* __restrict__ g3,
    const float* __restrict__ beta3, float* __restrict__ feats)
{
    __shared__ float smem[16 * 16 * 18];   // 18.4 KB: 16-ch chunk, col-padded
    const int img = blockIdx.x;
    const int tid = threadIdx.x;
    const int sp = tid & 63, oy = sp >> 3, ox = sp & 7;
    const int w = __builtin_amdgcn_readfirstlane(tid >> 6);   // wave 0..3
    const int ocq = blockIdx.y * 128 + w * 32;                // this wave's oc base
    const float inv = 1.0f / sqrtf(1.0f + 1e-5f);

    float acc[32];
    #pragma unroll
    for (int i = 0; i < 32; ++i) acc[i] = 0.f;

    for (int i = tid; i < 16 * 16; i += 256) smem[i * 18] = 0.f;  // left pad col

    const float* h2i = h2 + (size_t)img * (128 * 256);
    for (int cc = 0; cc < 8; ++cc) {
        __syncthreads();   // previous chunk fully consumed
        // load 16-channel chunk: 4096 floats = 1024 float4
        const float4* src = (const float4*)(h2i + (size_t)cc * 16 * 256);
        for (int i = tid; i < 1024; i += 256) {
            float4 v = src[i];
            int flat = i * 4, ic = flat >> 8, p = flat & 255, y = p >> 4, xx = p & 15;
            float* dst = &smem[ic * 288 + y * 18 + xx + 1];
            dst[0] = v.x; dst[1] = v.y; dst[2] = v.z; dst[3] = v.w;
        }
        __syncthreads();

        for (int ic = 0; ic < 16; ++ic) {
            float v[9];
            #pragma unroll
            for (int dy = 0; dy < 3; ++dy) {
                int r = 2 * oy - 1 + dy;           // only r=-1 invalid
                #pragma unroll
                for (int dx = 0; dx < 3; ++dx)
                    v[dy * 3 + dx] = (r >= 0) ? smem[ic * 288 + r * 18 + 2 * ox + dx] : 0.f;
            }
            const int icg = cc * 16 + ic;
            #pragma unroll
            for (int i = 0; i < 32; ++i) {          // ocq wave-uniform -> s_load weights
                const float* wp = w3 + ((size_t)(ocq + i) * 128 + icg) * 9;
                float s = acc[i];
                #pragma unroll
                for (int k = 0; k < 9; ++k) s += v[k] * wp[k];
                acc[i] = s;
            }
        }
    }

    // bn3+relu then pool: per-wave butterfly sum over the 64 spatial lanes
    float keep = 0.f;
    #pragma unroll
    for (int i = 0; i < 32; ++i) {
        int c = ocq + i;
        float A  = g3[c] * inv;
        float Bb = cb3[c] * A + beta3[c];
        float val = fmaxf(acc[i] * A + Bb, 0.f);
        #pragma unroll
        for (int off = 32; off; off >>= 1) val += __shfl_xor(val, off);
        if (sp == i) keep = val;
    }
    if (sp < 32)
        feats[(size_t)img * 256 + ocq + sp] = keep * (1.f / 64.f);
}

// ---------------- Kernel 3: router + top-2 + softmax gates -----------------
// grid 512, block 256 = 4 waves, one token per wave.
__global__ __launch_bounds__(256) void router_kernel(
    const float* __restrict__ feats, const float* __restrict__ rw,
    const float* __restrict__ rb, int* __restrict__ tidx,
    float* __restrict__ tgate)
{
    const int t = blockIdx.x * 4 + (threadIdx.x >> 6);
    const int lane = threadIdx.x & 63;
    float4 f = ((const float4*)(feats + (size_t)t * 256))[lane];
    float lg[16];
    #pragma unroll
    for (int e = 0; e < 16; ++e) {
        float4 w = ((const float4*)(rw + (size_t)e * 256))[lane];
        float p = f.x * w.x + f.y * w.y + f.z * w.z + f.w * w.w;
        #pragma unroll
        for (int off = 32; off; off >>= 1) p += __shfl_xor(p, off);
        lg[e] = p + rb[e];
    }
    // top-2, lowest index wins ties (matches lax.top_k)
    int i1 = 0; float m1 = lg[0];
    #pragma unroll
    for (int e = 1; e < 16; ++e) if (lg[e] > m1) { m1 = lg[e]; i1 = e; }
    int i2 = -1; float m2 = -1e30f;
    #pragma unroll
    for (int e = 0; e < 16; ++e)
        if (e != i1 && lg[e] > m2) { m2 = lg[e]; i2 = e; }
    if (i2 < 0) i2 = 0;                 // defensive: never emit -1
    float ex = expf(m2 - m1);
    float gA = 1.f / (1.f + ex);
    float gB = ex / (1.f + ex);
    if (lane == 0) {
        tidx[t * 2] = i1; tidx[t * 2 + 1] = i2;
        tgate[t * 2] = gA; tgate[t * 2 + 1] = gB;
    }
}

// ---------------- Kernel 4: top-2 expert MLP dispatch ----------------------
// grid 2048 (token), block 256.
__global__ __launch_bounds__(256) void moe_kernel(
    const float* __restrict__ feats, const int* __restrict__ tidx,
    const float* __restrict__ tgate,
    const float* __restrict__ ew1, const float* __restrict__ eb1,
    const float* __restrict__ ew2, const float* __restrict__ eb2,
    float* __restrict__ mixed)
{
    __shared__ float fr[256];
    __shared__ float hl[1024];
    const int t = blockIdx.x, tid = threadIdx.x;
    fr[tid] = feats[(size_t)t * 256 + tid];
    float macc = 0.f;
    for (int s = 0; s < 2; ++s) {
        const int e = tidx[t * 2 + s] & 15;   // clamp: OOB-proof
        const float g = tgate[t * 2 + s];
        __syncthreads();   // fr visible (s=0); hl safe to overwrite (s=1)
        // layer1: thread computes hidden units 4*tid..4*tid+3
        const float* W1 = ew1 + (size_t)e * (256 * 1024);
        float4 a = ((const float4*)(eb1 + (size_t)e * 1024))[tid];
        for (int d = 0; d < 256; ++d) {
            const float fv = fr[d];
            float4 w = ((const float4*)(W1 + (size_t)d * 1024))[tid];
            a.x += fv * w.x; a.y += fv * w.y; a.z += fv * w.z; a.w += fv * w.w;
        }
        a.x = fmaxf(a.x, 0.f); a.y = fmaxf(a.y, 0.f);
        a.z = fmaxf(a.z, 0.f); a.w = fmaxf(a.w, 0.f);
        ((float4*)hl)[tid] = a;
        __syncthreads();
        // layer2: thread computes output dim i = tid
        const float* W2 = ew2 + (size_t)e * (1024 * 256);
        float o0 = eb2[(size_t)e * 256 + tid], o1 = 0.f, o2 = 0.f, o3 = 0.f;
        for (int h = 0; h < 1024; h += 4) {
            o0 += hl[h]     * W2[(size_t)h       * 256 + tid];
            o1 += hl[h + 1] * W2[(size_t)(h + 1) * 256 + tid];
            o2 += hl[h + 2] * W2[(size_t)(h + 2) * 256 + tid];
            o3 += hl[h + 3] * W2[(size_t)(h + 3) * 256 + tid];
        }
        macc += g * ((o0 + o1) + (o2 + o3));
    }
    mixed[(size_t)t * 256 + tid] = macc;
}

// ---------------- Kernel 5: classifier head (fp32 out) ---------------------
// grid 512, block 256: 4 tokens per block, thread covers 4 columns.
__global__ __launch_bounds__(256) void head_kernel(
    const float* __restrict__ mixed, const float* __restrict__ hw,
    const float* __restrict__ hb, float* __restrict__ out)
{
    const int t0 = blockIdx.x * 4, tid = threadIdx.x;
    const float* m0 = mixed + (size_t)t0 * 256;   // uniform index -> scalar loads
    #pragma unroll
    for (int r = 0; r < 4; ++r) {
        int c = tid + 256 * r;
        if (c < 1000) {
            const float4* wr = (const float4*)(hw + (size_t)c * 256);
            float a0 = 0.f, a1 = 0.f, a2 = 0.f, a3 = 0.f;
            for (int d = 0; d < 64; ++d) {
                float4 w = wr[d];
                const float* q0 = m0 + 4 * d;
                a0 += w.x * q0[0]   + w.y * q0[1]   + w.z * q0[2]   + w.w * q0[3];
                a1 += w.x * q0[256] + w.y * q0[257] + w.z * q0[258] + w.w * q0[259];
                a2 += w.x * q0[512] + w.y * q0[513] + w.z * q0[514] + w.w * q0[515];
                a3 += w.x * q0[768] + w.y * q0[769] + w.z * q0[770] + w.w * q0[771];
            }
            float bb = hb[c];
            out[(size_t)(t0 + 0) * 1000 + c] = a0 + bb;
            out[(size_t)(t0 + 1) * 1000 + c] = a1 + bb;
            out[(size_t)(t0 + 2) * 1000 + c] = a2 + bb;
            out[(size_t)(t0 + 3) * 1000 + c] = a3 + bb;
        }
    }
}

// ---------------------------------------------------------------------------
extern "C" void kernel_launch(void* const* d_in, const int* in_sizes, int n_in,
                              void* d_out, int out_size, void* d_ws, size_t ws_size,
                              hipStream_t stream)
{
    const float* x       = (const float*)d_in[0];
    const float* conv1_w = (const float*)d_in[1];
    const float* conv1_b = (const float*)d_in[2];
    const float* bn1_g   = (const float*)d_in[3];
    const float* bn1_b   = (const float*)d_in[4];
    const float* conv2_w = (const float*)d_in[5];
    const float* conv2_b = (const float*)d_in[6];
    const float* bn2_g   = (const float*)d_in[7];
    const float* bn2_b   = (const float*)d_in[8];
    const float* conv3_w = (const float*)d_in[9];
    const float* conv3_b = (const float*)d_in[10];
    const float* bn3_g   = (const float*)d_in[11];
    const float* bn3_b   = (const float*)d_in[12];
    const float* router_w = (const float*)d_in[13];
    const float* router_b = (const float*)d_in[14];
    const float* ew1 = (const float*)d_in[15];
    const float* eb1 = (const float*)d_in[16];
    const float* ew2 = (const float*)d_in[17];
    const float* eb2 = (const float*)d_in[18];
    const float* head_w = (const float*)d_in[19];
    const float* head_b = (const float*)d_in[20];
    // top_k (d_in[21]) fixed at 2.

    // ---- workspace layout (total ~71.4 MB; R2 empirically proved this
    //      footprint is mapped and safe) -----------------------------------
    char* ws = (char*)d_ws;
    size_t off = 0;
    auto A = [&](size_t bytes) -> char* {
        char* p = ws + off; off += (bytes + 255) & ~(size_t)255; return p;
    };
    float* h2    = (float*)A(512ull * 128 * 256 * 4);   // 67.1 MB (per chunk)
    float* feats = (float*)A(2048ull * 256 * 4);        //  2.10 MB
    float* mixed = (float*)A(2048ull * 256 * 4);        //  2.10 MB
    int*   tidx  = (int*)  A(2048ull * 2 * 4);
    float* tgate = (float*)A(2048ull * 2 * 4);
    float* outp  = (float*)d_out;

    // ---- stem (4 chunks of 512 images, h2 reused) -------------------------
    const int CHUNK = 512;
    for (int c0 = 0; c0 < 2048; c0 += CHUNK) {
        conv12_kernel<<<dim3(CHUNK, 4), 256, 0, stream>>>(
            x + (size_t)c0 * 3072, conv1_w, conv1_b, bn1_g, bn1_b,
            conv2_w, conv2_b, bn2_g, bn2_b, h2);
        conv3pool_kernel<<<dim3(CHUNK, 2), 256, 0, stream>>>(
            h2, conv3_w, conv3_b, bn3_g, bn3_b, feats + (size_t)c0 * 256);
    }
    router_kernel<<<512, 256, 0, stream>>>(feats, router_w, router_b, tidx, tgate);
    moe_kernel<<<2048, 256, 0, stream>>>(feats, tidx, tgate, ew1, eb1, ew2, eb2, mixed);
    head_kernel<<<512, 256, 0, stream>>>(mixed, head_w, head_b, outp);
}

// Round 13
// 4852.942 us; speedup vs baseline: 1.7447x; 1.2738x over previous
//
#include <hip/hip_runtime.h>
#include <hip/hip_bf16.h>

// ---------------------------------------------------------------------------
// LiteCNNMoEClassifier on MI355X — round 13 (= rounds 9-12 resubmitted; GPU
// acquisition timed out four times before the kernel ever ran).
// R8 post-mortem: occupancy stuck at 24% (no min-waves bound), VALUBusy 37%,
// bank conflicts 6.2e7 from conv1's scalar LDS row reads, x4 conv1 recompute.
// This round (math bit-identical):
//   * __launch_bounds__(256,4) -> VGPR<=128, 4 blocks/CU target.
//   * conv12: oc=64/block (halves conv1 dup, doubles FMA per s_load weight),
//     conv1 row loads hoisted (4x fewer LDS reads), LDS 32.4KB.
//   * conv3pool unchanged + launch bound.
// ---------------------------------------------------------------------------

// ---------------- Kernel 1: conv1+bn1+relu fused into conv2+bn2+relu -------
// grid (512, 2): image x 64-oc half. block 256 = 16x16 spatial.
__global__ __launch_bounds__(256, 4) void conv12_kernel(
    const float* __restrict__ x,
    const float* __restrict__ w1, const float* __restrict__ cb1,
    const float* __restrict__ g1, const float* __restrict__ beta1,
    const float* __restrict__ w2, const float* __restrict__ cb2,
    const float* __restrict__ g2, const float* __restrict__ beta2,
    float* __restrict__ h2out)
{
    __shared__ float xt[3 * 34 * 34];    // padded input image (13.9 KB)
    __shared__ float h1t[4 * 34 * 34];   // padded h1 chunk, 4 ch (18.5 KB)
    const int img = blockIdx.x;
    const int ocb = blockIdx.y * 64;
    const int tid = threadIdx.x;
    const float inv = 1.0f / sqrtf(1.0f + 1e-5f);   // BN: var=1, eps=1e-5

    for (int i = tid; i < 3 * 34 * 34; i += 256) xt[i] = 0.f;
    for (int i = tid; i < 4 * 34 * 34; i += 256) h1t[i] = 0.f;
    __syncthreads();

    // load fp32 image into padded LDS
    const float4* xi = (const float4*)(x + (size_t)img * 3072);
    for (int i = tid; i < 768; i += 256) {
        float4 v = xi[i];
        int flat = i * 4;
        int ic = flat >> 10, p = flat & 1023, y = p >> 5, xx = p & 31;
        float* dst = &xt[ic * 1156 + (y + 1) * 34 + xx + 1];
        dst[0] = v.x; dst[1] = v.y; dst[2] = v.z; dst[3] = v.w;
    }
    __syncthreads();

    const int oy = tid >> 4, ox = tid & 15;      // conv2 output position
    const int yy = tid >> 3, x0 = (tid & 7) * 4; // conv1 output row / 4-col group

    float acc[64];
    #pragma unroll
    for (int i = 0; i < 64; ++i) acc[i] = 0.f;

    for (int ci = 0; ci < 16; ++ci) {            // 4 h1 channels per iteration
        // ---- conv1: channels ci*4..ci*4+3, row loads hoisted across j ----
        float s[4][4];
        #pragma unroll
        for (int j = 0; j < 4; ++j)
            #pragma unroll
            for (int c = 0; c < 4; ++c) s[j][c] = 0.f;

        #pragma unroll
        for (int ic = 0; ic < 3; ++ic) {
            float r[3][6];
            #pragma unroll
            for (int dy = 0; dy < 3; ++dy) {
                const float* row = &xt[ic * 1156 + (yy + dy) * 34 + x0];
                #pragma unroll
                for (int c = 0; c < 6; ++c) r[dy][c] = row[c];
            }
            #pragma unroll
            for (int j = 0; j < 4; ++j) {        // j uniform -> scalar weight loads
                const float* wp = w1 + (ci * 4 + j) * 27 + ic * 9;
                #pragma unroll
                for (int dy = 0; dy < 3; ++dy) {
                    float wa = wp[dy * 3], wb = wp[dy * 3 + 1], wc = wp[dy * 3 + 2];
                    s[j][0] += r[dy][0] * wa + r[dy][1] * wb + r[dy][2] * wc;
                    s[j][1] += r[dy][1] * wa + r[dy][2] * wb + r[dy][3] * wc;
                    s[j][2] += r[dy][2] * wa + r[dy][3] * wb + r[dy][4] * wc;
                    s[j][3] += r[dy][3] * wa + r[dy][4] * wb + r[dy][5] * wc;
                }
            }
        }
        #pragma unroll
        for (int j = 0; j < 4; ++j) {
            const int oc1 = ci * 4 + j;
            float A  = g1[oc1] * inv;
            float Bb = cb1[oc1] * A + beta1[oc1];
            float* dst = &h1t[j * 1156 + (yy + 1) * 34 + x0 + 1];
            dst[0] = fmaxf(s[j][0] * A + Bb, 0.f);
            dst[1] = fmaxf(s[j][1] * A + Bb, 0.f);
            dst[2] = fmaxf(s[j][2] * A + Bb, 0.f);
            dst[3] = fmaxf(s[j][3] * A + Bb, 0.f);
        }
        __syncthreads();

        // ---- conv2 partial accumulation over these 4 input channels ------
        for (int ic4 = 0; ic4 < 4; ++ic4) {
            float v[9];
            #pragma unroll
            for (int dy = 0; dy < 3; ++dy)
                #pragma unroll
                for (int dx = 0; dx < 3; ++dx)
                    v[dy * 3 + dx] = h1t[ic4 * 1156 + (2 * oy + dy) * 34 + 2 * ox + dx];
            const int icg = ci * 4 + ic4;
            #pragma unroll
            for (int oc = 0; oc < 64; ++oc) {    // uniform weight index -> s_load
                const float* wp = w2 + ((size_t)(ocb + oc) * 64 + icg) * 9;
                float s2 = acc[oc];
                #pragma unroll
                for (int k = 0; k < 9; ++k) s2 += v[k] * wp[k];
                acc[oc] = s2;
            }
        }
        __syncthreads();
    }

    float* outp = h2out + ((size_t)img * 128 + ocb) * 256 + oy * 16 + ox;
    #pragma unroll
    for (int oc = 0; oc < 64; ++oc) {
        int c = ocb + oc;
        float A  = g2[c] * inv;
        float Bb = cb2[c] * A + beta2[c];
        outp[(size_t)oc * 256] = fmaxf(acc[oc] * A + Bb, 0.f);
    }
}

// ---------------- Kernel 2: conv3+bn3+relu + global avg pool ---------------
// grid (512, 2): image x 128-oc half. block 256 = 64 spatial x 4 waves(32 oc).
__global__ __launch_bounds__(256, 4) void conv3pool_kernel(
    const float* __restrict__ h2, const float* __restrict__ w3,
    const float* __restrict__ cb3, const float* __restrict__ g3,
    const float* __restrict__ beta3, float* __restrict__ feats)
{
    __shared__ float smem[16 * 16 * 18];   // 18.4 KB: 16-ch chunk, col-padded
    const int img = blockIdx.x;
    const int tid = threadIdx.x;
    const int sp = tid & 63, oy = sp >> 3, ox = sp & 7;
    const int w = __builtin_amdgcn_readfirstlane(tid >> 6);   // wave 0..3
    const int ocq = blockIdx.y * 128 + w * 32;                // this wave's oc base
    const float inv = 1.0f / sqrtf(1.0f + 1e-5f);

    float acc[32];
    #pragma unroll
    for (int i = 0; i < 32; ++i) acc[i] = 0.f;

    for (int i = tid; i < 16 * 16; i += 256) smem[i * 18] = 0.f;  // left pad col

    const float* h2i = h2 + (size_t)img * (128 * 256);
    for (int cc = 0; cc < 8; ++cc) {
        __syncthreads();   // previous chunk fully consumed
        // load 16-channel chunk: 4096 floats = 1024 float4
        const float4* src = (const float4*)(h2i + (size_t)cc * 16 * 256);
        for (int i = tid; i < 1024; i += 256) {
            float4 v = src[i];
            int flat = i * 4, ic = flat >> 8, p = flat & 255, y = p >> 4, xx = p & 15;
            float* dst = &smem[ic * 288 + y * 18 + xx + 1];
            dst[0] = v.x; dst[1] = v.y; dst[2] = v.z; dst[3] = v.w;
        }
        __syncthreads();

        for (int ic = 0; ic < 16; ++ic) {
            float v[9];
            #pragma unroll
            for (int dy = 0; dy < 3; ++dy) {
                int r = 2 * oy - 1 + dy;           // only r=-1 invalid
                #pragma unroll
                for (int dx = 0; dx < 3; ++dx)
                    v[dy * 3 + dx] = (r >= 0) ? smem[ic * 288 + r * 18 + 2 * ox + dx] : 0.f;
            }
            const int icg = cc * 16 + ic;
            #pragma unroll
            for (int i = 0; i < 32; ++i) {          // ocq wave-uniform -> s_load weights
                const float* wp = w3 + ((size_t)(ocq + i) * 128 + icg) * 9;
                float s = acc[i];
                #pragma unroll
                for (int k = 0; k < 9; ++k) s += v[k] * wp[k];
                acc[i] = s;
            }
        }
    }

    // bn3+relu then pool: per-wave butterfly sum over the 64 spatial lanes
    float keep = 0.f;
    #pragma unroll
    for (int i = 0; i < 32; ++i) {
        int c = ocq + i;
        float A  = g3[c] * inv;
        float Bb = cb3[c] * A + beta3[c];
        float val = fmaxf(acc[i] * A + Bb, 0.f);
        #pragma unroll
        for (int off = 32; off; off >>= 1) val += __shfl_xor(val, off);
        if (sp == i) keep = val;
    }
    if (sp < 32)
        feats[(size_t)img * 256 + ocq + sp] = keep * (1.f / 64.f);
}

// ---------------- Kernel 3: router + top-2 + softmax gates -----------------
// grid 512, block 256 = 4 waves, one token per wave.
__global__ __launch_bounds__(256) void router_kernel(
    const float* __restrict__ feats, const float* __restrict__ rw,
    const float* __restrict__ rb, int* __restrict__ tidx,
    float* __restrict__ tgate)
{
    const int t = blockIdx.x * 4 + (threadIdx.x >> 6);
    const int lane = threadIdx.x & 63;
    float4 f = ((const float4*)(feats + (size_t)t * 256))[lane];
    float lg[16];
    #pragma unroll
    for (int e = 0; e < 16; ++e) {
        float4 w = ((const float4*)(rw + (size_t)e * 256))[lane];
        float p = f.x * w.x + f.y * w.y + f.z * w.z + f.w * w.w;
        #pragma unroll
        for (int off = 32; off; off >>= 1) p += __shfl_xor(p, off);
        lg[e] = p + rb[e];
    }
    // top-2, lowest index wins ties (matches lax.top_k)
    int i1 = 0; float m1 = lg[0];
    #pragma unroll
    for (int e = 1; e < 16; ++e) if (lg[e] > m1) { m1 = lg[e]; i1 = e; }
    int i2 = -1; float m2 = -1e30f;
    #pragma unroll
    for (int e = 0; e < 16; ++e)
        if (e != i1 && lg[e] > m2) { m2 = lg[e]; i2 = e; }
    if (i2 < 0) i2 = 0;                 // defensive: never emit -1
    float ex = expf(m2 - m1);
    float gA = 1.f / (1.f + ex);
    float gB = ex / (1.f + ex);
    if (lane == 0) {
        tidx[t * 2] = i1; tidx[t * 2 + 1] = i2;
        tgate[t * 2] = gA; tgate[t * 2 + 1] = gB;
    }
}

// ---------------- Kernel 4: top-2 expert MLP dispatch ----------------------
// grid 2048 (token), block 256.
__global__ __launch_bounds__(256) void moe_kernel(
    const float* __restrict__ feats, const int* __restrict__ tidx,
    const float* __restrict__ tgate,
    const float* __restrict__ ew1, const float* __restrict__ eb1,
    const float* __restrict__ ew2, const float* __restrict__ eb2,
    float* __restrict__ mixed)
{
    __shared__ float fr[256];
    __shared__ float hl[1024];
    const int t = blockIdx.x, tid = threadIdx.x;
    fr[tid] = feats[(size_t)t * 256 + tid];
    float macc = 0.f;
    for (int s = 0; s < 2; ++s) {
        const int e = tidx[t * 2 + s] & 15;   // clamp: OOB-proof
        const float g = tgate[t * 2 + s];
        __syncthreads();   // fr visible (s=0); hl safe to overwrite (s=1)
        // layer1: thread computes hidden units 4*tid..4*tid+3
        const float* W1 = ew1 + (size_t)e * (256 * 1024);
        float4 a = ((const float4*)(eb1 + (size_t)e * 1024))[tid];
        for (int d = 0; d < 256; ++d) {
            const float fv = fr[d];
            float4 w = ((const float4*)(W1 + (size_t)d * 1024))[tid];
            a.x += fv * w.x; a.y += fv * w.y; a.z += fv * w.z; a.w += fv * w.w;
        }
        a.x = fmaxf(a.x, 0.f); a.y = fmaxf(a.y, 0.f);
        a.z = fmaxf(a.z, 0.f); a.w = fmaxf(a.w, 0.f);
        ((float4*)hl)[tid] = a;
        __syncthreads();
        // layer2: thread computes output dim i = tid
        const float* W2 = ew2 + (size_t)e * (1024 * 256);
        float o0 = eb2[(size_t)e * 256 + tid], o1 = 0.f, o2 = 0.f, o3 = 0.f;
        for (int h = 0; h < 1024; h += 4) {
            o0 += hl[h]     * W2[(size_t)h       * 256 + tid];
            o1 += hl[h + 1] * W2[(size_t)(h + 1) * 256 + tid];
            o2 += hl[h + 2] * W2[(size_t)(h + 2) * 256 + tid];
            o3 += hl[h + 3] * W2[(size_t)(h + 3) * 256 + tid];
        }
        macc += g * ((o0 + o1) + (o2 + o3));
    }
    mixed[(size_t)t * 256 + tid] = macc;
}

// ---------------- Kernel 5: classifier head (fp32 out) ---------------------
// grid 512, block 256: 4 tokens per block, thread covers 4 columns.
__global__ __launch_bounds__(256) void head_kernel(
    const float* __restrict__ mixed, const float* __restrict__ hw,
    const float* __restrict__ hb, float* __restrict__ out)
{
    const int t0 = blockIdx.x * 4, tid = threadIdx.x;
    const float* m0 = mixed + (size_t)t0 * 256;   // uniform index -> scalar loads
    #pragma unroll
    for (int r = 0; r < 4; ++r) {
        int c = tid + 256 * r;
        if (c < 1000) {
            const float4* wr = (const float4*)(hw + (size_t)c * 256);
            float a0 = 0.f, a1 = 0.f, a2 = 0.f, a3 = 0.f;
            for (int d = 0; d < 64; ++d) {
                float4 w = wr[d];
                const float* q0 = m0 + 4 * d;
                a0 += w.x * q0[0]   + w.y * q0[1]   + w.z * q0[2]   + w.w * q0[3];
                a1 += w.x * q0[256] + w.y * q0[257] + w.z * q0[258] + w.w * q0[259];
                a2 += w.x * q0[512] + w.y * q0[513] + w.z * q0[514] + w.w * q0[515];
                a3 += w.x * q0[768] + w.y * q0[769] + w.z * q0[770] + w.w * q0[771];
            }
            float bb = hb[c];
            out[(size_t)(t0 + 0) * 1000 + c] = a0 + bb;
            out[(size_t)(t0 + 1) * 1000 + c] = a1 + bb;
            out[(size_t)(t0 + 2) * 1000 + c] = a2 + bb;
            out[(size_t)(t0 + 3) * 1000 + c] = a3 + bb;
        }
    }
}

// ---------------------------------------------------------------------------
extern "C" void kernel_launch(void* const* d_in, const int* in_sizes, int n_in,
                              void* d_out, int out_size, void* d_ws, size_t ws_size,
                              hipStream_t stream)
{
    const float* x       = (const float*)d_in[0];
    const float* conv1_w = (const float*)d_in[1];
    const float* conv1_b = (const float*)d_in[2];
    const float* bn1_g   = (const float*)d_in[3];
    const float* bn1_b   = (const float*)d_in[4];
    const float* conv2_w = (const float*)d_in[5];
    const float* conv2_b = (const float*)d_in[6];
    const float* bn2_g   = (const float*)d_in[7];
    const float* bn2_b   = (const float*)d_in[8];
    const float* conv3_w = (const float*)d_in[9];
    const float* conv3_b = (const float*)d_in[10];
    const float* bn3_g   = (const float*)d_in[11];
    const float* bn3_b   = (const float*)d_in[12];
    const float* router_w = (const float*)d_in[13];
    const float* router_b = (const float*)d_in[14];
    const float* ew1 = (const float*)d_in[15];
    const float* eb1 = (const float*)d_in[16];
    const float* ew2 = (const float*)d_in[17];
    const float* eb2 = (const float*)d_in[18];
    const float* head_w = (const float*)d_in[19];
    const float* head_b = (const float*)d_in[20];
    // top_k (d_in[21]) fixed at 2.

    // ---- workspace layout (total ~71.4 MB; R2/R8 empirically proved this
    //      footprint is mapped and safe) -----------------------------------
    char* ws = (char*)d_ws;
    size_t off = 0;
    auto A = [&](size_t bytes) -> char* {
        char* p = ws + off; off += (bytes + 255) & ~(size_t)255; return p;
    };
    float* h2    = (float*)A(512ull * 128 * 256 * 4);   // 67.1 MB (per chunk)
    float* feats = (float*)A(2048ull * 256 * 4);        //  2.10 MB
    float* mixed = (float*)A(2048ull * 256 * 4);        //  2.10 MB
    int*   tidx  = (int*)  A(2048ull * 2 * 4);
    float* tgate = (float*)A(2048ull * 2 * 4);
    float* outp  = (float*)d_out;

    // ---- stem (4 chunks of 512 images, h2 reused) -------------------------
    const int CHUNK = 512;
    for (int c0 = 0; c0 < 2048; c0 += CHUNK) {
        conv12_kernel<<<dim3(CHUNK, 2), 256, 0, stream>>>(
            x + (size_t)c0 * 3072, conv1_w, conv1_b, bn1_g, bn1_b,
            conv2_w, conv2_b, bn2_g, bn2_b, h2);
        conv3pool_kernel<<<dim3(CHUNK, 2), 256, 0, stream>>>(
            h2, conv3_w, conv3_b, bn3_g, bn3_b, feats + (size_t)c0 * 256);
    }
    router_kernel<<<512, 256, 0, stream>>>(feats, router_w, router_b, tidx, tgate);
    moe_kernel<<<2048, 256, 0, stream>>>(feats, tidx, tgate, ew1, eb1, ew2, eb2, mixed);
    head_kernel<<<512, 256, 0, stream>>>(mixed, head_w, head_b, outp);
}